// Round 1
// baseline (2051.554 us; speedup 1.0000x reference)
//
#include <hip/hip_runtime.h>

typedef float f32x4 __attribute__((ext_vector_type(4)));
typedef int   i32x4 __attribute__((ext_vector_type(4)));

#define KDIM   2112   // N_STATE + N_U
#define NST    2048
#define NYD    128
#define NUD    64
#define BATCHD 256

__device__ __forceinline__ unsigned short f2bf(float f) {
  unsigned int u = __builtin_bit_cast(unsigned int, f);
  u = (u + 0x7FFFu + ((u >> 16) & 1u)) >> 16;
  return (unsigned short)u;
}

__device__ __forceinline__ float tanh_fast(float x) {
  float ax = __builtin_fabsf(x);
  float e  = __expf(-2.0f * ax);
  float r  = (1.0f - e) / (1.0f + e);
  return __builtin_copysignf(r, x);
}

__device__ __forceinline__ void gl_lds16(const unsigned short* g, unsigned short* l) {
  __builtin_amdgcn_global_load_lds(
      (const __attribute__((address_space(1))) unsigned int*)g,
      (__attribute__((address_space(3))) unsigned int*)l, 16, 0, 0);
}

// ---- prep 1: A[2112][2048] f32 -> At[2048][2112] bf16 (At[n][k] = A[k][n])
__global__ void k_prepA(const float* __restrict__ A, unsigned short* __restrict__ At) {
  __shared__ float tile[64][65];
  int nbase = blockIdx.x * 64;
  int kbase = blockIdx.y * 64;
  int tx = threadIdx.x & 63;
  int ty = threadIdx.x >> 6;   // 0..3
  for (int r = 0; r < 64; r += 4)
    tile[r + ty][tx] = A[(size_t)(kbase + r + ty) * NST + nbase + tx];
  __syncthreads();
  for (int r = 0; r < 64; r += 4) {
    int ni = r + ty;
    At[(size_t)(nbase + ni) * KDIM + kbase + tx] = f2bf(tile[tx][ni]);
  }
}

// ---- prep 2: X0 = tanh(concat(teacherforce(init,Y0), U0)) bf16, err0 = init - Y0
__global__ void k_prepX0(const float* __restrict__ U, const float* __restrict__ Y,
                         const float* __restrict__ init, unsigned short* __restrict__ X0,
                         float* __restrict__ out) {
  int m = blockIdx.x;
  int c = blockIdx.y * 256 + threadIdx.x;
  if (c >= KDIM) return;
  float v;
  if (c < NYD) {
    float y = Y[(size_t)m * NYD + c];       // Y[0][m][c]
    out[(size_t)m * NYD + c] = init[c] - y; // err0
    v = y;                                  // teacher-forced
  } else if (c < NST) {
    v = init[c];
  } else {
    v = U[(size_t)m * NUD + (c - NST)];     // U[0][m][*]
  }
  X0[(size_t)m * KDIM + c] = f2bf(tanh_fast(v));
}

// ---- per-step fused GEMM + epilogue.
// Computes state_s = Xc @ A (f32 acc), emits out[s] (err if s<64 else expectation),
// and writes Xn = next step's tanh activations (bf16), incl. teacher forcing and U-part.
#define MFMA(ACC, A_, B_) \
  asm("v_mfma_f32_16x16x32_bf16 %0, %1, %2, %0" : "+v"(ACC) : "v"(A_), "v"(B_))

__global__ void __launch_bounds__(64) k_step(const unsigned short* __restrict__ Xc,
                                             unsigned short* __restrict__ Xn,
                                             const unsigned short* __restrict__ At,
                                             const float* __restrict__ U,
                                             const float* __restrict__ Y,
                                             float* __restrict__ out, int s) {
  // LDS: X bufs [0,2048) ushorts (2 x 32x32), B bufs [2048,6144) (2 x 64x32)
  __shared__ __align__(16) unsigned short lds[6144];
  int bid = blockIdx.x;
  int xcd = bid & 7, idx = bid >> 3;
  int j = xcd * 4 + (idx & 3);   // 0..31  (N tile of 64) - XCD-local column slice
  int i = idx >> 2;              // 0..7   (M tile of 32)
  int Mb = i * 32, Nb = j * 64;
  int lane = threadIdx.x;

  // staging constants: lane -> (row-in-16, src chunk with XOR pre-swizzle)
  int sr = lane >> 2;                          // 0..15
  int g8 = (((lane & 3) ^ ((lane >> 3) & 3)) << 3);
  const unsigned short* xs0 = Xc + (size_t)(Mb +      sr) * KDIM + g8;
  const unsigned short* xs1 = Xc + (size_t)(Mb + 16 + sr) * KDIM + g8;
  const unsigned short* bs0 = At + (size_t)(Nb +      sr) * KDIM + g8;
  const unsigned short* bs1 = At + (size_t)(Nb + 16 + sr) * KDIM + g8;
  const unsigned short* bs2 = At + (size_t)(Nb + 32 + sr) * KDIM + g8;
  const unsigned short* bs3 = At + (size_t)(Nb + 48 + sr) * KDIM + g8;

#define STAGE(it2, b) do { int kb = (it2) << 5;                       \
    gl_lds16(xs0 + kb, lds + (b) * 1024);                             \
    gl_lds16(xs1 + kb, lds + (b) * 1024 + 512);                       \
    gl_lds16(bs0 + kb, lds + 2048 + (b) * 2048);                      \
    gl_lds16(bs1 + kb, lds + 2048 + (b) * 2048 + 512);                \
    gl_lds16(bs2 + kb, lds + 2048 + (b) * 2048 + 1024);               \
    gl_lds16(bs3 + kb, lds + 2048 + (b) * 2048 + 1536);               \
  } while (0)

  // frag-read constants (ushort offsets, 16B aligned): swizzled chunk = kh ^ ((row>>1)&3)
  int row = lane & 15, kh = lane >> 4;
  int fo = row * 32 + (((kh ^ ((row >> 1) & 3))) << 3);

  f32x4 acc00 = {0.f,0.f,0.f,0.f}, acc01 = {0.f,0.f,0.f,0.f};
  f32x4 acc02 = {0.f,0.f,0.f,0.f}, acc03 = {0.f,0.f,0.f,0.f};
  f32x4 acc10 = {0.f,0.f,0.f,0.f}, acc11 = {0.f,0.f,0.f,0.f};
  f32x4 acc12 = {0.f,0.f,0.f,0.f}, acc13 = {0.f,0.f,0.f,0.f};

  STAGE(0, 0);
  STAGE(1, 1);

#define ITER(it, VM) do {                                             \
    asm volatile("s_waitcnt vmcnt(" #VM ")" ::: "memory");            \
    __builtin_amdgcn_sched_barrier(0);                                \
    const unsigned short* xb = lds + ((it) & 1) * 1024;               \
    const unsigned short* bb = lds + 2048 + ((it) & 1) * 2048;        \
    i32x4 a0 = *(const i32x4*)(xb + fo);                              \
    i32x4 a1 = *(const i32x4*)(xb + 512 + fo);                        \
    i32x4 b0 = *(const i32x4*)(bb + fo);                              \
    i32x4 b1 = *(const i32x4*)(bb + 512 + fo);                        \
    i32x4 b2 = *(const i32x4*)(bb + 1024 + fo);                       \
    i32x4 b3 = *(const i32x4*)(bb + 1536 + fo);                       \
    MFMA(acc00, a0, b0); MFMA(acc01, a0, b1);                         \
    MFMA(acc02, a0, b2); MFMA(acc03, a0, b3);                         \
    MFMA(acc10, a1, b0); MFMA(acc11, a1, b1);                         \
    MFMA(acc12, a1, b2); MFMA(acc13, a1, b3);                         \
    asm volatile("s_waitcnt lgkmcnt(0)" ::: "memory");                \
    __builtin_amdgcn_sched_barrier(0);                                \
    if ((it) + 2 < 66) STAGE((it) + 2, (it) & 1);                     \
  } while (0)

#pragma unroll 2
  for (int it = 0; it < 65; ++it) ITER(it, 6);
  ITER(65, 0);

  // ---- fused epilogue ----
  int col16 = lane & 15, row4 = (lane >> 4) << 2;
  bool past = s < 64;

#define EPI(ACC, MB, CB) do {                                         \
    _Pragma("unroll")                                                 \
    for (int r = 0; r < 4; ++r) {                                     \
      int m = Mb + (MB) * 16 + row4 + r;                              \
      int n = Nb + (CB) * 16 + col16;                                 \
      float v = ACC[r]; float xv;                                     \
      if (n < NYD) {                                                  \
        size_t oo = ((size_t)s * BATCHD + m) * NYD + n;               \
        if (past) { float y = Y[oo]; out[oo] = v - y; xv = tanh_fast(y); } \
        else      { out[oo] = v; xv = tanh_fast(v); }                 \
      } else xv = tanh_fast(v);                                       \
      Xn[(size_t)m * KDIM + n] = f2bf(xv);                            \
    }                                                                 \
  } while (0)

  EPI(acc00, 0, 0); EPI(acc01, 0, 1); EPI(acc02, 0, 2); EPI(acc03, 0, 3);
  EPI(acc10, 1, 0); EPI(acc11, 1, 1); EPI(acc12, 1, 2); EPI(acc13, 1, 3);

  // U-part of next X: cols 2048..2112 (j==0 WGs copy their 32 rows)
  if (j == 0) {
#pragma unroll 4
    for (int rr = 0; rr < 32; ++rr) {
      int m = Mb + rr;
      float u = U[((size_t)s * BATCHD + m) * NUD + lane];
      Xn[(size_t)m * KDIM + NST + lane] = f2bf(tanh_fast(u));
    }
  }
}

extern "C" void kernel_launch(void* const* d_in, const int* in_sizes, int n_in,
                              void* d_out, int out_size, void* d_ws, size_t ws_size,
                              hipStream_t stream) {
  (void)in_sizes; (void)n_in; (void)out_size; (void)ws_size;
  const float* U    = (const float*)d_in[0];   // [80][256][64]
  const float* Y    = (const float*)d_in[1];   // [64][256][128]
  const float* A    = (const float*)d_in[2];   // [2112][2048]
  const float* init = (const float*)d_in[3];   // [1][2048]
  float* out = (float*)d_out;                  // [80][256][128]

  char* ws = (char*)d_ws;
  unsigned short* At = (unsigned short*)ws;                        //  8,650,752 B
  unsigned short* X0 = (unsigned short*)(ws + 8650752);            //  1,081,344 B
  unsigned short* X1 = (unsigned short*)(ws + 8650752 + 1081344);  //  1,081,344 B

  k_prepA<<<dim3(32, 33), 256, 0, stream>>>(A, At);
  k_prepX0<<<dim3(256, 9), 256, 0, stream>>>(U, Y, init, X0, out);

  for (int t = 0; t < 79; ++t) {
    const unsigned short* xc = (t & 1) ? X1 : X0;
    unsigned short*       xn = (t & 1) ? X0 : X1;
    k_step<<<256, 64, 0, stream>>>(xc, xn, At, U, Y, out, t + 1);
  }
}